// Round 7
// baseline (224.796 us; speedup 1.0000x reference)
//
#include <hip/hip_runtime.h>

#define BB 8192
#define TT 512
#define II 5
#define HH 16
#define TC 32                       // steps per LDS chunk
#define NC (TT / TC)                // 16 chunks
#define CHUNK_BYTES (16 * TC * 32)  // 16 batches * 32 steps * 32B records

typedef _Float16 half_t;
typedef _Float16 half4 __attribute__((ext_vector_type(4)));
typedef __fp16 fp16x2 __attribute__((ext_vector_type(2)));
typedef float floatx4 __attribute__((ext_vector_type(4)));
typedef unsigned int uint32;
typedef uint32 uint2v __attribute__((ext_vector_type(2)));

__device__ __forceinline__ void gl_lds16(const void* g, void* l) {
    __builtin_amdgcn_global_load_lds(
        (const __attribute__((address_space(1))) void*)g,
        (__attribute__((address_space(3))) void*)l, 16, 0, 0);
}

// Per-wave GRU: 16 batches / wave, 1 wave / block (no barriers anywhere).
// MFMA 16x16x16 f16, D-layout == B-layout: gate output feeds next step's B
// operand in-lane. All transcendentals replaced by a 513-entry LDS tanh
// table with linear interp (sigma(x) = 0.5 + 0.5*tanh(x/2), the 1/2 folded
// into the r/z weights). x staged via global_load_lds DMA, double-buffered,
// counted vmcnt; records XOR-swizzled (source-side) to kill bank conflicts.
__global__ __launch_bounds__(64)
void gru_fwd_kernel(const float* __restrict__ x,
                    const float* __restrict__ W_ih,
                    const float* __restrict__ W_hh,
                    const float* __restrict__ b_ih,
                    const float* __restrict__ b_hh,
                    const float* __restrict__ W_fc,
                    const float* __restrict__ b_fc,
                    float* __restrict__ out) {
    __shared__ __align__(16) char ldsbuf[2][CHUNK_BYTES];
    __shared__ float lds_tab[513];

    const int lane = threadIdx.x;   // 0..63
    const int jb   = lane & 15;     // batch within tile (B/D column, A row)
    const int q    = lane >> 4;     // k-group
    const int b0   = blockIdx.x * 16;

    // ---- build tanh table (single wave per block; DS in-order, no barrier)
    for (int i = lane; i < 513; i += 64)
        lds_tab[i] = tanhf(fmaf((float)i, 0.015625f, -4.0f));
    asm volatile("s_waitcnt lgkmcnt(0)" ::: "memory");

    // ---- resident A-fragments. r/z scaled by 0.5 (sigma-via-tanh trick).
    half4 wa_r, wa_z, wa_n, wx_r, wx_z, wx_n;
#pragma unroll
    for (int j = 0; j < 4; ++j) {
        int k = 4 * q + j;
        wa_r[j] = (half_t)(0.5f * W_hh[(0 * HH + jb) * HH + k]);
        wa_z[j] = (half_t)(0.5f * W_hh[(1 * HH + jb) * HH + k]);
        wa_n[j] = (half_t)W_hh[(2 * HH + jb) * HH + k];
        float vr = (k < II) ? W_ih[(0 * HH + jb) * II + k] : 0.0f;
        float vz = (k < II) ? W_ih[(1 * HH + jb) * II + k] : 0.0f;
        float vn = (k < II) ? W_ih[(2 * HH + jb) * II + k] : 0.0f;
        wx_r[j] = (half_t)(0.5f * vr); wx_z[j] = (half_t)(0.5f * vz);
        wx_n[j] = (half_t)vn;
    }

    // ---- bias C-fragments (row = 4q+i); r/z scaled by 0.5
    floatx4 cb_r, cb_z, cb_xn, cb_hn;
#pragma unroll
    for (int i = 0; i < 4; ++i) {
        int r = 4 * q + i;
        cb_r[i]  = 0.5f * (b_ih[r] + b_hh[r]);
        cb_z[i]  = 0.5f * (b_ih[HH + r] + b_hh[HH + r]);
        cb_xn[i] = b_ih[2 * HH + r];
        cb_hn[i] = b_hh[2 * HH + r];
    }

    // ---- loop-carried state
    half4 bh = {};                                        // h as B-fragment
    float hf0 = 0.0f, hf1 = 0.0f, hf2 = 0.0f, hf3 = 0.0f; // h rows 4q+i (f32)

    // ---- DMA source swizzle: LDS slot l of batch k holds record-part
    // (s,h) with l' = l ^ (k&7), s = l'>>1, h = l'&1. off8[m] = source byte
    // offset for this lane under XOR-mask m.
    int off8[8];
#pragma unroll
    for (int m = 0; m < 8; ++m) {
        int lp = lane ^ m;
        off8[m] = (lp >> 1) * (II * 4) + (lp & 1) * 4;
    }

#define ISSUE(C)                                                              \
    do {                                                                      \
        if ((C) < NC) {                                                       \
            const char* cb_ = (const char*)x                                  \
                + ((size_t)b0 * TT + (size_t)(C) * TC) * (II * 4);            \
            char* db_ = &ldsbuf[(C) & 1][0];                                  \
            _Pragma("unroll")                                                 \
            for (int k_ = 0; k_ < 16; ++k_)                                   \
                gl_lds16(cb_ + (size_t)k_ * (TT * II * 4) + off8[k_ & 7],     \
                         db_ + k_ * 1024);                                    \
        }                                                                     \
    } while (0)

    // tanh via table + linear interp (all full-rate VALU + 1 DS read pair)
#define TLUT(RES, Y)                                                          \
    do {                                                                      \
        float u_ = fmaf((Y), 64.0f, 256.0f);                                  \
        u_ = __builtin_amdgcn_fmed3f(u_, 0.0f, 511.999f);                     \
        int i_ = (int)u_;                                                     \
        float fr_ = u_ - (float)i_;                                           \
        float a_ = lds_tab[i_];                                               \
        float b_ = lds_tab[i_ + 1];                                           \
        RES = fmaf(fr_, b_ - a_, a_);                                         \
    } while (0)

#define GEL(I)                                                                \
    do {                                                                      \
        float tr_, tz_, tn_;                                                  \
        TLUT(tr_, d_r[I]);                                                    \
        TLUT(tz_, d_z[I]);                                                    \
        float r_ = fmaf(0.5f, tr_, 0.5f);                                     \
        float z_ = fmaf(0.5f, tz_, 0.5f);                                     \
        TLUT(tn_, fmaf(r_, d_n[I], cx_n[I]));                                 \
        hf##I = fmaf(z_, hf##I - tn_, tn_);                                   \
    } while (0)

    // One GRU step; PF = raw 16B record half (q0: x0..x3, q1: x1..x4).
#define STEP(PF)                                                              \
    do {                                                                      \
        fp16x2 pk01_ = __builtin_amdgcn_cvt_pkrtz(PF[0], PF[1]);              \
        fp16x2 pk23_ = __builtin_amdgcn_cvt_pkrtz(PF[2], PF[3]);              \
        fp16x2 pk4_  = __builtin_amdgcn_cvt_pkrtz(PF[3], 0.0f);               \
        uint32 lo_ = (q == 0) ? __builtin_bit_cast(uint32, pk01_)             \
                   : ((q == 1) ? __builtin_bit_cast(uint32, pk4_) : 0u);      \
        uint32 hi_ = (q == 0) ? __builtin_bit_cast(uint32, pk23_) : 0u;       \
        uint2v bxu_ = {lo_, hi_};                                             \
        half4 bx = __builtin_bit_cast(half4, bxu_);                           \
        floatx4 cx_r = __builtin_amdgcn_mfma_f32_16x16x16f16(wx_r, bx, cb_r, 0, 0, 0); \
        floatx4 cx_z = __builtin_amdgcn_mfma_f32_16x16x16f16(wx_z, bx, cb_z, 0, 0, 0); \
        floatx4 cx_n = __builtin_amdgcn_mfma_f32_16x16x16f16(wx_n, bx, cb_xn, 0, 0, 0); \
        floatx4 d_r  = __builtin_amdgcn_mfma_f32_16x16x16f16(wa_r, bh, cx_r, 0, 0, 0); \
        floatx4 d_z  = __builtin_amdgcn_mfma_f32_16x16x16f16(wa_z, bh, cx_z, 0, 0, 0); \
        floatx4 d_n  = __builtin_amdgcn_mfma_f32_16x16x16f16(wa_n, bh, cb_hn, 0, 0, 0); \
        GEL(0); GEL(1); GEL(2); GEL(3);                                       \
        fp16x2 lo2_ = __builtin_amdgcn_cvt_pkrtz(hf0, hf1);                   \
        fp16x2 hi2_ = __builtin_amdgcn_cvt_pkrtz(hf2, hf3);                   \
        bh[0] = (half_t)lo2_[0]; bh[1] = (half_t)lo2_[1];                     \
        bh[2] = (half_t)hi2_[0]; bh[3] = (half_t)hi2_[1];                     \
    } while (0)

    ISSUE(0);
    ISSUE(1);

    // Read-side swizzle constants (match write-side involution):
    // byte offset in batch's 1KB = (s*32 + (q&1)*16) ^ ((jb&7)<<4)
    const int swz   = (jb & 7) << 4;
    const int lobit = ((q & 1) * 16) ^ (swz & 16);
    const int swzhi = swz & 96;

    for (int c = 0; c < NC; ++c) {
        // Wait for chunk c's 16 loads; keep chunk c+1's 16 in flight.
        if (c == NC - 1) asm volatile("s_waitcnt vmcnt(0)" ::: "memory");
        else             asm volatile("s_waitcnt vmcnt(16)" ::: "memory");

        const char* myrec = &ldsbuf[c & 1][0] + jb * 1024 + lobit;

        floatx4 pfA = *(const floatx4*)(myrec + ((0 * 32) ^ swzhi));
        floatx4 pfB;
#pragma unroll
        for (int s = 0; s < TC; s += 2) {
            pfB = *(const floatx4*)(myrec + (((s + 1) * 32) ^ swzhi));
            STEP(pfA);
            if (s + 2 < TC)
                pfA = *(const floatx4*)(myrec + (((s + 2) * 32) ^ swzhi));
            STEP(pfB);
        }

        ISSUE(c + 2);   // after all reads of buf[c&1]; lands well before use
    }
#undef ISSUE
#undef STEP
#undef GEL
#undef TLUT

    // ---- out[b] = dot(W_fc, h) + b_fc ; reduce across the 4 k-groups
    float p = hf0 * W_fc[4 * q + 0];
    p = fmaf(hf1, W_fc[4 * q + 1], p);
    p = fmaf(hf2, W_fc[4 * q + 2], p);
    p = fmaf(hf3, W_fc[4 * q + 3], p);
    p += __shfl_xor(p, 16);
    p += __shfl_xor(p, 32);
    if (q == 0) out[b0 + jb] = p + b_fc[0];
}

extern "C" void kernel_launch(void* const* d_in, const int* in_sizes, int n_in,
                              void* d_out, int out_size, void* d_ws, size_t ws_size,
                              hipStream_t stream) {
    const float* x    = (const float*)d_in[0];
    const float* W_ih = (const float*)d_in[1];
    const float* W_hh = (const float*)d_in[2];
    const float* b_ih = (const float*)d_in[3];
    const float* b_hh = (const float*)d_in[4];
    const float* W_fc = (const float*)d_in[5];
    const float* b_fc = (const float*)d_in[6];
    float* out = (float*)d_out;

    dim3 grid(BB / 16);   // one 64-lane wave per 16 batches
    dim3 block(64);
    gru_fwd_kernel<<<grid, block, 0, stream>>>(x, W_ih, W_hh, b_ih, b_hh, W_fc, b_fc, out);
}

// Round 8
// 141.794 us; speedup vs baseline: 1.5854x; 1.5854x over previous
//
#include <hip/hip_runtime.h>

#define BB 8192
#define TT 512
#define II 5
#define HH 16
#define TC 32                       // steps per LDS chunk
#define NC (TT / TC)                // 16 chunks
#define CHUNK_BYTES (16 * TC * 32)  // 16 batches * 32 steps * 32B records

typedef _Float16 half_t;
typedef _Float16 half4 __attribute__((ext_vector_type(4)));
typedef __fp16 fp16x2 __attribute__((ext_vector_type(2)));
typedef float floatx4 __attribute__((ext_vector_type(4)));
typedef unsigned int uint32;
typedef uint32 uint2v __attribute__((ext_vector_type(2)));

__device__ __forceinline__ float fast_sigmoid(float x) {
    float e = __builtin_amdgcn_exp2f(x * -1.4426950408889634f);
    return __builtin_amdgcn_rcpf(1.0f + e);
}
__device__ __forceinline__ float fast_tanh(float x) {
    float e = __builtin_amdgcn_exp2f(x * 2.8853900817779268f);
    return fmaf(-2.0f, __builtin_amdgcn_rcpf(e + 1.0f), 1.0f);
}

__device__ __forceinline__ void gl_lds16(const void* g, void* l) {
    __builtin_amdgcn_global_load_lds(
        (const __attribute__((address_space(1))) void*)g,
        (__attribute__((address_space(3))) void*)l, 16, 0, 0);
}

// Per-wave GRU: 16 batches / wave, 1 wave / block (no barriers anywhere).
// MFMA 16x16x16 f16, D-layout == B-layout: gate output feeds next step's B
// operand in-lane. x staged via global_load_lds DMA, double-buffered,
// counted vmcnt; records XOR-swizzled (source-side) so x ds_reads are
// conflict-free. Inner loop NOT unrolled (#pragma unroll 1) so the hot body
// (~2.5 KB) stays resident in the 32 KB L1 I-cache — R5-R7's fully-unrolled
// 38 KB bodies streamed code from L2 every chunk (VALUBusy 32% vs R1's 70%).
__global__ __launch_bounds__(64)
void gru_fwd_kernel(const float* __restrict__ x,
                    const float* __restrict__ W_ih,
                    const float* __restrict__ W_hh,
                    const float* __restrict__ b_ih,
                    const float* __restrict__ b_hh,
                    const float* __restrict__ W_fc,
                    const float* __restrict__ b_fc,
                    float* __restrict__ out) {
    __shared__ __align__(16) char ldsbuf[2][CHUNK_BYTES];

    const int lane = threadIdx.x;   // 0..63
    const int jb   = lane & 15;     // batch within tile (B/D column, A row)
    const int q    = lane >> 4;     // k-group
    const int b0   = blockIdx.x * 16;

    // ---- resident A-fragments: W_hh gate rows; W_ih rows zero-padded to K=16
    half4 wa_r, wa_z, wa_n, wx_r, wx_z, wx_n;
#pragma unroll
    for (int j = 0; j < 4; ++j) {
        int k = 4 * q + j;
        wa_r[j] = (half_t)W_hh[(0 * HH + jb) * HH + k];
        wa_z[j] = (half_t)W_hh[(1 * HH + jb) * HH + k];
        wa_n[j] = (half_t)W_hh[(2 * HH + jb) * HH + k];
        float vr = (k < II) ? W_ih[(0 * HH + jb) * II + k] : 0.0f;
        float vz = (k < II) ? W_ih[(1 * HH + jb) * II + k] : 0.0f;
        float vn = (k < II) ? W_ih[(2 * HH + jb) * II + k] : 0.0f;
        wx_r[j] = (half_t)vr; wx_z[j] = (half_t)vz; wx_n[j] = (half_t)vn;
    }

    // ---- bias C-fragments (row = 4q+i, uniform over batch columns)
    floatx4 cb_r, cb_z, cb_xn, cb_hn;
#pragma unroll
    for (int i = 0; i < 4; ++i) {
        int r = 4 * q + i;
        cb_r[i]  = b_ih[r] + b_hh[r];
        cb_z[i]  = b_ih[HH + r] + b_hh[HH + r];
        cb_xn[i] = b_ih[2 * HH + r];
        cb_hn[i] = b_hh[2 * HH + r];
    }

    // ---- loop-carried state
    half4 bh = {};                                        // h as B-fragment
    float hf0 = 0.0f, hf1 = 0.0f, hf2 = 0.0f, hf3 = 0.0f; // h rows 4q+i (f32)

    // ---- DMA source swizzle: LDS slot l of batch k holds record-part
    // (s,h) with l' = l ^ (k&7), s = l'>>1, h = l'&1.
    int off8[8];
#pragma unroll
    for (int m = 0; m < 8; ++m) {
        int lp = lane ^ m;
        off8[m] = (lp >> 1) * (II * 4) + (lp & 1) * 4;
    }

#define ISSUE(C)                                                              \
    do {                                                                      \
        if ((C) < NC) {                                                       \
            const char* cb_ = (const char*)x                                  \
                + ((size_t)b0 * TT + (size_t)(C) * TC) * (II * 4);            \
            char* db_ = &ldsbuf[(C) & 1][0];                                  \
            _Pragma("unroll")                                                 \
            for (int k_ = 0; k_ < 16; ++k_)                                   \
                gl_lds16(cb_ + (size_t)k_ * (TT * II * 4) + off8[k_ & 7],     \
                         db_ + k_ * 1024);                                    \
        }                                                                     \
    } while (0)

    // One GRU step; PF = raw 16B record half (q0: x0..x3, q1: x1..x4).
#define STEP(PF)                                                              \
    do {                                                                      \
        fp16x2 pk01_ = __builtin_amdgcn_cvt_pkrtz(PF[0], PF[1]);              \
        fp16x2 pk23_ = __builtin_amdgcn_cvt_pkrtz(PF[2], PF[3]);              \
        fp16x2 pk4_  = __builtin_amdgcn_cvt_pkrtz(PF[3], 0.0f);               \
        uint32 lo_ = (q == 0) ? __builtin_bit_cast(uint32, pk01_)             \
                   : ((q == 1) ? __builtin_bit_cast(uint32, pk4_) : 0u);      \
        uint32 hi_ = (q == 0) ? __builtin_bit_cast(uint32, pk23_) : 0u;       \
        uint2v bxu_ = {lo_, hi_};                                             \
        half4 bx = __builtin_bit_cast(half4, bxu_);                           \
        floatx4 cx_r = __builtin_amdgcn_mfma_f32_16x16x16f16(wx_r, bx, cb_r, 0, 0, 0); \
        floatx4 cx_z = __builtin_amdgcn_mfma_f32_16x16x16f16(wx_z, bx, cb_z, 0, 0, 0); \
        floatx4 cx_n = __builtin_amdgcn_mfma_f32_16x16x16f16(wx_n, bx, cb_xn, 0, 0, 0); \
        floatx4 d_r  = __builtin_amdgcn_mfma_f32_16x16x16f16(wa_r, bh, cx_r, 0, 0, 0); \
        floatx4 d_z  = __builtin_amdgcn_mfma_f32_16x16x16f16(wa_z, bh, cx_z, 0, 0, 0); \
        floatx4 d_n  = __builtin_amdgcn_mfma_f32_16x16x16f16(wa_n, bh, cb_hn, 0, 0, 0); \
        float r0 = fast_sigmoid(d_r[0]), z0 = fast_sigmoid(d_z[0]);           \
        float n0 = fast_tanh(fmaf(r0, d_n[0], cx_n[0]));                      \
        hf0 = fmaf(z0, hf0 - n0, n0);                                         \
        float r1 = fast_sigmoid(d_r[1]), z1 = fast_sigmoid(d_z[1]);           \
        float n1 = fast_tanh(fmaf(r1, d_n[1], cx_n[1]));                      \
        hf1 = fmaf(z1, hf1 - n1, n1);                                         \
        float r2 = fast_sigmoid(d_r[2]), z2 = fast_sigmoid(d_z[2]);           \
        float n2 = fast_tanh(fmaf(r2, d_n[2], cx_n[2]));                      \
        hf2 = fmaf(z2, hf2 - n2, n2);                                         \
        float r3 = fast_sigmoid(d_r[3]), z3 = fast_sigmoid(d_z[3]);           \
        float n3 = fast_tanh(fmaf(r3, d_n[3], cx_n[3]));                      \
        hf3 = fmaf(z3, hf3 - n3, n3);                                         \
        fp16x2 lo2_ = __builtin_amdgcn_cvt_pkrtz(hf0, hf1);                   \
        fp16x2 hi2_ = __builtin_amdgcn_cvt_pkrtz(hf2, hf3);                   \
        bh[0] = (half_t)lo2_[0]; bh[1] = (half_t)lo2_[1];                     \
        bh[2] = (half_t)hi2_[0]; bh[3] = (half_t)hi2_[1];                     \
    } while (0)

    ISSUE(0);
    ISSUE(1);

    // Read-side swizzle constants (match write-side involution):
    // byte offset in batch's 1KB = (s*32 + (q&1)*16) ^ ((jb&7)<<4)
    const int swz   = (jb & 7) << 4;
    const int lobit = ((q & 1) * 16) ^ (swz & 16);
    const int swzhi = swz & 96;

    for (int c = 0; c < NC; ++c) {
        // Wait for chunk c's 16 loads; keep chunk c+1's 16 in flight.
        if (c == NC - 1) asm volatile("s_waitcnt vmcnt(0)" ::: "memory");
        else             asm volatile("s_waitcnt vmcnt(16)" ::: "memory");

        const char* myrec = &ldsbuf[c & 1][0] + jb * 1024 + lobit;

        floatx4 pfA = *(const floatx4*)(myrec + ((0 * 32) ^ swzhi));
        floatx4 pfB;
        // NOT unrolled: keep the hot body (~2.5 KB) L1 I-cache resident.
#pragma unroll 1
        for (int s = 0; s < TC; s += 2) {
            pfB = *(const floatx4*)(myrec + (((s + 1) * 32) ^ swzhi));
            STEP(pfA);
            // wrap at chunk end (harmless re-read of slot 0, branchless)
            pfA = *(const floatx4*)(myrec + ((((s + 2) & (TC - 1)) * 32) ^ swzhi));
            STEP(pfB);
        }

        ISSUE(c + 2);   // after all reads of buf[c&1]; lands well before use
    }
#undef ISSUE
#undef STEP

    // ---- out[b] = dot(W_fc, h) + b_fc ; reduce across the 4 k-groups
    float p = hf0 * W_fc[4 * q + 0];
    p = fmaf(hf1, W_fc[4 * q + 1], p);
    p = fmaf(hf2, W_fc[4 * q + 2], p);
    p = fmaf(hf3, W_fc[4 * q + 3], p);
    p += __shfl_xor(p, 16);
    p += __shfl_xor(p, 32);
    if (q == 0) out[b0 + jb] = p + b_fc[0];
}

extern "C" void kernel_launch(void* const* d_in, const int* in_sizes, int n_in,
                              void* d_out, int out_size, void* d_ws, size_t ws_size,
                              hipStream_t stream) {
    const float* x    = (const float*)d_in[0];
    const float* W_ih = (const float*)d_in[1];
    const float* W_hh = (const float*)d_in[2];
    const float* b_ih = (const float*)d_in[3];
    const float* b_hh = (const float*)d_in[4];
    const float* W_fc = (const float*)d_in[5];
    const float* b_fc = (const float*)d_in[6];
    float* out = (float*)d_out;

    dim3 grid(BB / 16);   // one 64-lane wave per 16 batches
    dim3 block(64);
    gru_fwd_kernel<<<grid, block, 0, stream>>>(x, W_ih, W_hh, b_ih, b_hh, W_fc, b_fc, out);
}